// Round 5
// baseline (298.412 us; speedup 1.0000x reference)
//
#include <hip/hip_runtime.h>
#include <hip/hip_bf16.h>

#define BB   256
#define II   1152
#define DIN  8
#define OO   10
#define DOUT 16
#define NIBM 32        // stored i-planes (block-level reduced)
#define CHUNK 9        // i per wave (1152 / (NIBM*4))

// Pass kernel, batch-on-lanes: lane = dsub*32 + b_local.
// Each lane owns batch b = bg*32+b_local and d-half dsub (8 d's in registers).
// w loads are uniform within each 32-lane half -> 2 cache segments per instr.
// Routing dot over d: 8 in-register FMAs + one shfl_xor(32).
// Block = 4 waves stacked on i (ib = ibM*4 + wv), LDS-reduced to s_partial[NIBM].
template<int K>
__global__ __launch_bounds__(256, 1) void pass_kernel(
    const float* __restrict__ x,   // fp32 [B][I][DIN]
    const float* __restrict__ w,   // fp32 [O][I][DOUT][DIN]
    const float* __restrict__ V,   // fp32 [B][O][DOUT]
    float* __restrict__ sp)        // fp32 [NIBM][B][O][DOUT]
{
  const int tid  = threadIdx.x;
  const int lane = tid & 63;
  const int wv   = tid >> 6;
  const int bl   = lane & 31;
  const int dsub = lane >> 5;          // which d-half this lane owns
  const int bg   = blockIdx.y;
  const int b    = bg * 32 + bl;
  const int ibM  = blockIdx.x;
  const int i0   = (ibM * 4 + wv) * CHUNK;

  float Vr[OO][8];
  if (K >= 1) {
#pragma unroll
    for (int o = 0; o < OO; ++o) {
      const float* vp = V + (b * OO + o) * DOUT + dsub * 8;
      const float4 va = *(const float4*)(vp);
      const float4 vb = *(const float4*)(vp + 4);
      Vr[o][0]=va.x; Vr[o][1]=va.y; Vr[o][2]=va.z; Vr[o][3]=va.w;
      Vr[o][4]=vb.x; Vr[o][5]=vb.y; Vr[o][6]=vb.z; Vr[o][7]=vb.w;
    }
  }
  float s[OO][8];
#pragma unroll
  for (int o = 0; o < OO; ++o)
#pragma unroll
    for (int dd = 0; dd < 8; ++dd) s[o][dd] = 0.f;

#pragma unroll 1
  for (int ii = 0; ii < CHUNK; ++ii) {
    const int i = i0 + ii;
    const float* xp = x + ((size_t)b * II + i) * DIN;
    const float4 x0 = *(const float4*)(xp);
    const float4 x1 = *(const float4*)(xp + 4);

    float xh[OO][8];
    float t[OO];
#pragma unroll
    for (int o = 0; o < OO; ++o) {
      const float4* wp = (const float4*)(w + (((size_t)o * II + i) * DOUT + dsub * 8) * DIN);
#pragma unroll
      for (int dd = 0; dd < 8; ++dd) {
        const float4 wa = wp[2 * dd];
        const float4 wb = wp[2 * dd + 1];
        float a;
        a  = wa.x * x0.x + wa.y * x0.y + wa.z * x0.z + wa.w * x0.w;
        a += wb.x * x1.x + wb.y * x1.y + wb.z * x1.z + wb.w * x1.w;
        xh[o][dd] = a;
      }
      if (K >= 1) {
        float tp = 0.f;
#pragma unroll
        for (int dd = 0; dd < 8; ++dd) tp += Vr[o][dd] * xh[o][dd];
        t[o] = tp;
      }
    }

    if (K == 0) {
#pragma unroll
      for (int o = 0; o < OO; ++o)
#pragma unroll
        for (int dd = 0; dd < 8; ++dd) s[o][dd] += xh[o][dd];
    } else {
#pragma unroll
      for (int o = 0; o < OO; ++o)
        t[o] += __shfl_xor(t[o], 32, 64);    // combine the two d-halves
      float e[OO];
      float sum = 0.f;
#pragma unroll
      for (int o = 0; o < OO; ++o) { e[o] = __expf(t[o]); sum += e[o]; }
      const float inv = __builtin_amdgcn_rcpf(sum);
#pragma unroll
      for (int o = 0; o < OO; ++o) {
        const float c = e[o] * inv;
#pragma unroll
        for (int dd = 0; dd < 8; ++dd) s[o][dd] += c * xh[o][dd];
      }
    }
  }

  if (K == 0) {
#pragma unroll
    for (int o = 0; o < OO; ++o)
#pragma unroll
      for (int dd = 0; dd < 8; ++dd) s[o][dd] *= 0.1f;   // uniform softmax weight
  }

  // Block-level reduction over the 4 i-stacked waves. Two phases (one per
  // d-half) to fit LDS. red stride 81: bank = (17*b + idx) % 32, conflict-free.
  __shared__ float red[4][32][81];
#pragma unroll 1
  for (int half = 0; half < 2; ++half) {
    if (dsub == half) {
#pragma unroll
      for (int o = 0; o < OO; ++o)
#pragma unroll
        for (int dd = 0; dd < 8; ++dd)
          red[wv][bl][o * 8 + dd] = s[o][dd];
    }
    __syncthreads();
    for (int k = tid; k < 32 * 80; k += 256) {
      const int rb = k / 80, idx = k % 80;
      const float v = red[0][rb][idx] + red[1][rb][idx]
                    + red[2][rb][idx] + red[3][rb][idx];
      const int o = idx >> 3, dd = idx & 7;
      sp[(((size_t)ibM * BB + bg * 32 + rb) * OO + o) * DOUT + half * 8 + dd] = v;
    }
    __syncthreads();
  }
}

// Combine partials over NIBM i-planes, squash, update V / write final output.
template<int K>
__global__ __launch_bounds__(256) void reduce_kernel(
    const float* __restrict__ s_partial,   // [NIBM][B*O*DOUT]
    float* __restrict__ V,                 // [B*O*DOUT]
    float* __restrict__ out)               // fp32 [B*O*DOUT]
{
  const int idx = blockIdx.x * 256 + threadIdx.x;    // over B*O*DOUT = 40960
  float s = 0.f;
#pragma unroll
  for (int ib = 0; ib < NIBM; ++ib)
    s += s_partial[(size_t)ib * (BB * OO * DOUT) + idx];

  // squash over the 16 Dout lanes (contiguous 16-lane groups share (b,o))
  float sq = s * s;
  sq += __shfl_xor(sq, 1);
  sq += __shfl_xor(sq, 2);
  sq += __shfl_xor(sq, 4);
  sq += __shfl_xor(sq, 8);
  const float mag = sqrtf(sq);
  const float v = sq / (1.f + sq) * (s / (mag + 1e-8f));

  if (K == 0)      V[idx] = v;
  else if (K == 1) V[idx] += v;
  else             out[idx] = v;
}

extern "C" void kernel_launch(void* const* d_in, const int* in_sizes, int n_in,
                              void* d_out, int out_size, void* d_ws, size_t ws_size,
                              hipStream_t stream) {
  const float* x = (const float*)d_in[0];   // fp32 [256,1152,8]
  const float* w = (const float*)d_in[1];   // fp32 [10,1152,16,8]
  float* out = (float*)d_out;               // fp32 [256,10,16]

  float* s_partial = (float*)d_ws;                              // NIBM*B*O*DOUT floats (5.2 MB)
  float* V = s_partial + (size_t)NIBM * BB * OO * DOUT;         // B*O*DOUT floats

  dim3 pg(NIBM, 8);                        // 256 blocks, 1 per CU
  const int rg = (BB * OO * DOUT) / 256;   // 160 blocks

  pass_kernel<0><<<pg, 256, 0, stream>>>(x, w, V, s_partial);
  reduce_kernel<0><<<rg, 256, 0, stream>>>(s_partial, V, out);
  pass_kernel<1><<<pg, 256, 0, stream>>>(x, w, V, s_partial);
  reduce_kernel<1><<<rg, 256, 0, stream>>>(s_partial, V, out);
  pass_kernel<2><<<pg, 256, 0, stream>>>(x, w, V, s_partial);
  reduce_kernel<2><<<rg, 256, 0, stream>>>(s_partial, V, out);
}